// Round 1
// baseline (19650.632 us; speedup 1.0000x reference)
//
#include <hip/hip_runtime.h>
#include <hip/hip_cooperative_groups.h>

namespace cg = cooperative_groups;

// Problem constants
#define BB 128
#define TT 512
#define HH 512
#define K4H 2048
#define KTOT 1024   // combined K: k<512 -> h@Wh, k>=512 -> x@Wx

typedef short bfrag  __attribute__((ext_vector_type(8)));   // 8 bf16 (4 VGPRs)
typedef float facc   __attribute__((ext_vector_type(16)));  // 16 f32 acc
typedef unsigned short u16;
typedef unsigned short ushortx8 __attribute__((ext_vector_type(8)));

__device__ __forceinline__ u16 f2bf(float x){
    unsigned u = __builtin_bit_cast(unsigned, x);
    unsigned r = (u + 0x7fffu + ((u >> 16) & 1u)) >> 16;   // RNE
    return (u16)r;
}
__device__ __forceinline__ float bf2f(u16 h){
    unsigned u = ((unsigned)h) << 16;
    return __builtin_bit_cast(float, u);
}
__device__ __forceinline__ float fast_tanh(float x){
    float e = __expf(2.f * x);
    return 1.f - 2.f * __builtin_amdgcn_rcpf(e + 1.f);
}
__device__ __forceinline__ float fast_sig(float x){
    return __builtin_amdgcn_rcpf(1.f + __expf(-x));
}

// ---- prep: X -> bf16 hi/lo split ----
__global__ void prep_x(const float* __restrict__ X, u16* __restrict__ Xhi, u16* __restrict__ Xlo){
    size_t g = (size_t)blockIdx.x * blockDim.x + threadIdx.x;   // one float4 per thread
    float4 v = ((const float4*)X)[g];
    u16 h0 = f2bf(v.x), h1 = f2bf(v.y), h2 = f2bf(v.z), h3 = f2bf(v.w);
    ushort4 hh; hh.x = h0; hh.y = h1; hh.z = h2; hh.w = h3;
    ushort4 ll;
    ll.x = f2bf(v.x - bf2f(h0)); ll.y = f2bf(v.y - bf2f(h1));
    ll.z = f2bf(v.z - bf2f(h2)); ll.w = f2bf(v.w - bf2f(h3));
    ((ushort4*)Xhi)[g] = hh;
    ((ushort4*)Xlo)[g] = ll;
}

// ---- prep: transpose+split weights into WT[c][k], k = [Wh rows 0..511 | Wx rows 0..511] ----
__global__ void prep_w(const float* __restrict__ Wx, const float* __restrict__ Wh,
                       u16* __restrict__ WThi, u16* __restrict__ WTlo){
    int c = blockIdx.x;  // 0..2047
    for (int kk = threadIdx.x; kk < KTOT; kk += blockDim.x){
        float w = (kk < 512) ? Wh[(size_t)kk * K4H + c] : Wx[(size_t)(kk - 512) * K4H + c];
        u16 hi = f2bf(w);
        u16 lo = f2bf(w - bf2f(hi));
        WThi[(size_t)c * KTOT + kk] = hi;
        WTlo[(size_t)c * KTOT + kk] = lo;
    }
}

// ---- prep: zero h buffers (buf 0) and out row t=0 (out is poisoned 0xAA each call) ----
__global__ void prep_misc(u16* __restrict__ hH, u16* __restrict__ hL, float* __restrict__ out){
    int i = blockIdx.x * blockDim.x + threadIdx.x;   // 65536 threads
    hH[i] = 0; hL[i] = 0;
    int b = i >> 9, j = i & 511;
    out[(size_t)b * (TT * HH) + j] = 0.f;            // out[b][0][j]
}

// ---- main cooperative kernel: 256 WGs (1/CU), 256 thr, 511 steps, 1 grid.sync/step ----
// WG = (bt = batch tile of 32, js = 8 h-indices). C-tile 32x32: row m = batch, col n = g*8+jl.
// Split-K over 4 waves (wave kh owns 128 of h-K and 128 of x-K). B-frags in registers (static).
__global__ void __launch_bounds__(256, 1) lstm_main(
    const u16* __restrict__ Xhi, const u16* __restrict__ Xlo,
    const u16* __restrict__ WThi, const u16* __restrict__ WTlo,
    const float* __restrict__ bias,
    u16* __restrict__ hH, u16* __restrict__ hL,
    float* __restrict__ out)
{
    __shared__ float red[4][32][36];   // pitch 36: <=2-way bank aliasing on write & read

    const int tid  = threadIdx.x;
    const int lane = tid & 63;
    const int kh   = tid >> 6;         // wave id = K-split index
    const int wid  = blockIdx.x;
    const int bt   = wid & 3;          // batch tile (32 batches)
    const int js   = wid >> 2;         // j-set (8 h-indices)

    const int n  = lane & 31;          // MFMA row/col within tile
    const int kg = (lane >> 5) * 8;    // k sub-group

    // B fragments: 32 k-tiles' worth held in VGPRs for the whole kernel (16 per wave x hi/lo)
    const int c_n = (n >> 3) * 512 + js * 8 + (n & 7);   // global column for frag col n
    bfrag bh[16], blo[16];
#pragma unroll
    for (int i = 0; i < 16; i++){
        int kk = (i < 8) ? (kh * 128 + i * 16 + kg)
                         : (512 + kh * 128 + (i - 8) * 16 + kg);
        bh[i]  = __builtin_bit_cast(bfrag, *(const ushortx8*)(WThi + (size_t)c_n * KTOT + kk));
        blo[i] = __builtin_bit_cast(bfrag, *(const ushortx8*)(WTlo + (size_t)c_n * KTOT + kk));
    }

    // A-fragment addressing (row m = n lane field)
    const int bgm = bt * 32 + n;                        // global batch row for A
    const size_t xrow = (size_t)bgm * (TT * 512);       // + t*512 + k
    const int xk    = kh * 128 + kg;
    const int hbase = bgm * 512 + kh * 128 + kg;

    // gate-thread mapping: one (batch, h-index) pair per thread; c-state in a register
    const int blt = tid >> 3;            // 0..31 batch local
    const int jl  = tid & 7;             // 0..7 h-index local
    const int bg  = bt * 32 + blt;
    const int jg  = js * 8 + jl;
    float biasr[4];
#pragma unroll
    for (int g = 0; g < 4; g++) biasr[g] = bias[g * 512 + jg];

    float c_state = 0.f;
    facc acc0 = {0.f,0.f,0.f,0.f,0.f,0.f,0.f,0.f,0.f,0.f,0.f,0.f,0.f,0.f,0.f,0.f};
    facc acc1 = {0.f,0.f,0.f,0.f,0.f,0.f,0.f,0.f,0.f,0.f,0.f,0.f,0.f,0.f,0.f,0.f};

    cg::grid_group grid = cg::this_grid();

    for (int t = 0; t < 511; t++){
        // ---- x-part GEMM (independent of h) BEFORE the sync: hides barrier latency ----
        const u16* xh = Xhi + xrow + (size_t)t * 512 + xk;
        const u16* xl = Xlo + xrow + (size_t)t * 512 + xk;
#pragma unroll
        for (int i = 0; i < 8; i++){
            bfrag ah = __builtin_bit_cast(bfrag, *(const ushortx8*)(xh + i * 16));
            bfrag al = __builtin_bit_cast(bfrag, *(const ushortx8*)(xl + i * 16));
            if (i & 1){
                acc1 = __builtin_amdgcn_mfma_f32_32x32x16_bf16(ah, bh[8+i],  acc1, 0, 0, 0);
                acc1 = __builtin_amdgcn_mfma_f32_32x32x16_bf16(ah, blo[8+i], acc1, 0, 0, 0);
                acc1 = __builtin_amdgcn_mfma_f32_32x32x16_bf16(al, bh[8+i],  acc1, 0, 0, 0);
            } else {
                acc0 = __builtin_amdgcn_mfma_f32_32x32x16_bf16(ah, bh[8+i],  acc0, 0, 0, 0);
                acc0 = __builtin_amdgcn_mfma_f32_32x32x16_bf16(ah, blo[8+i], acc0, 0, 0, 0);
                acc0 = __builtin_amdgcn_mfma_f32_32x32x16_bf16(al, bh[8+i],  acc0, 0, 0, 0);
            }
        }

        grid.sync();   // h_t fully written by all WGs (step t-1 epilogue)

        // ---- h-part GEMM ----
        const u16* hhp = hH + (size_t)(t & 1) * (BB * 512) + hbase;
        const u16* hlp = hL + (size_t)(t & 1) * (BB * 512) + hbase;
#pragma unroll
        for (int i = 0; i < 8; i++){
            bfrag ah = __builtin_bit_cast(bfrag, *(const ushortx8*)(hhp + i * 16));
            bfrag al = __builtin_bit_cast(bfrag, *(const ushortx8*)(hlp + i * 16));
            if (i & 1){
                acc1 = __builtin_amdgcn_mfma_f32_32x32x16_bf16(ah, bh[i],  acc1, 0, 0, 0);
                acc1 = __builtin_amdgcn_mfma_f32_32x32x16_bf16(ah, blo[i], acc1, 0, 0, 0);
                acc1 = __builtin_amdgcn_mfma_f32_32x32x16_bf16(al, bh[i],  acc1, 0, 0, 0);
            } else {
                acc0 = __builtin_amdgcn_mfma_f32_32x32x16_bf16(ah, bh[i],  acc0, 0, 0, 0);
                acc0 = __builtin_amdgcn_mfma_f32_32x32x16_bf16(ah, blo[i], acc0, 0, 0, 0);
                acc0 = __builtin_amdgcn_mfma_f32_32x32x16_bf16(al, bh[i],  acc0, 0, 0, 0);
            }
        }

        // ---- split-K reduction via LDS ----
        __syncthreads();   // previous step's gate reads of red are done
#pragma unroll
        for (int r = 0; r < 16; r++){
            int mrow = (r & 3) + 8 * (r >> 2) + 4 * (lane >> 5);  // m74/m101 verified C layout
            red[kh][mrow][n] = acc0[r] + acc1[r];
        }
        __syncthreads();

#pragma unroll
        for (int r = 0; r < 16; r++){ acc0[r] = 0.f; acc1[r] = 0.f; }

        // ---- gates + state update (one (b,j) per thread) ----
        float v[4];
#pragma unroll
        for (int g = 0; g < 4; g++){
            int nn = g * 8 + jl;
            v[g] = red[0][blt][nn] + red[1][blt][nn] + red[2][blt][nn] + red[3][blt][nn] + biasr[g];
        }
        // faithful to source: tanh BEFORE gating; h_next uses tanh of OLD c
        float Af = fast_tanh(v[0]);
        float Ag = fast_tanh(v[1]);
        float Ai = fast_tanh(v[2]);
        float Ao = fast_tanh(v[3]);
        float f_ = fast_sig(Af);
        float g_ = fast_tanh(Ag);
        float i_ = fast_sig(Ai);
        float o_ = fast_sig(Ao);
        float hnew = o_ * fast_tanh(c_state);
        c_state = f_ * c_state + g_ * i_;

        out[(size_t)bg * (TT * HH) + (size_t)(t + 1) * HH + jg] = hnew;
        u16 hhi = f2bf(hnew);
        size_t hidx = (size_t)((t + 1) & 1) * (BB * 512) + (size_t)bg * 512 + jg;
        hH[hidx] = hhi;
        hL[hidx] = f2bf(hnew - bf2f(hhi));
    }
}

extern "C" void kernel_launch(void* const* d_in, const int* in_sizes, int n_in,
                              void* d_out, int out_size, void* d_ws, size_t ws_size,
                              hipStream_t stream)
{
    const float* X    = (const float*)d_in[0];
    const float* Wx   = (const float*)d_in[1];
    const float* Wh   = (const float*)d_in[2];
    const float* bias = (const float*)d_in[3];
    float* out = (float*)d_out;

    char* ws = (char*)d_ws;
    u16* Xhi  = (u16*)(ws);                      // 64 MiB
    u16* Xlo  = (u16*)(ws + 67108864ull);        // 64 MiB
    u16* WThi = (u16*)(ws + 134217728ull);       // 4 MiB
    u16* WTlo = (u16*)(ws + 138412032ull);       // 4 MiB
    u16* hHp  = (u16*)(ws + 142606336ull);       // 256 KiB (double buffered)
    u16* hLp  = (u16*)(ws + 142868480ull);       // 256 KiB
    // total ws use: ~136.5 MiB

    hipLaunchKernelGGL(prep_x,    dim3(32768), dim3(256), 0, stream, X, Xhi, Xlo);
    hipLaunchKernelGGL(prep_w,    dim3(2048),  dim3(256), 0, stream, Wx, Wh, WThi, WTlo);
    hipLaunchKernelGGL(prep_misc, dim3(256),   dim3(256), 0, stream, hHp, hLp, out);

    void* args[] = { (void*)&Xhi, (void*)&Xlo, (void*)&WThi, (void*)&WTlo,
                     (void*)&bias, (void*)&hHp, (void*)&hLp, (void*)&out };
    hipLaunchCooperativeKernel(lstm_main, dim3(256), dim3(256), args, 0, stream);
}

// Round 2
// 8049.140 us; speedup vs baseline: 2.4413x; 2.4413x over previous
//
#include <hip/hip_runtime.h>

// Problem constants
#define BB 128
#define TT 512
#define HH 512
#define K4H 2048
#define KTOT 1024   // combined K: k<512 -> h@Wh, k>=512 -> x@Wx

typedef short bfrag  __attribute__((ext_vector_type(8)));   // 8 bf16 (4 VGPRs)
typedef float facc   __attribute__((ext_vector_type(16)));  // 16 f32 acc
typedef unsigned short u16;
typedef unsigned short ushortx8 __attribute__((ext_vector_type(8)));
typedef unsigned long long u64;
typedef u64 u64x2 __attribute__((ext_vector_type(2)));
typedef unsigned int u32;

__device__ __forceinline__ u16 f2bf(float x){
    unsigned u = __builtin_bit_cast(unsigned, x);
    unsigned r = (u + 0x7fffu + ((u >> 16) & 1u)) >> 16;   // RNE
    return (u16)r;
}
__device__ __forceinline__ float bf2f(u16 h){
    unsigned u = ((unsigned)h) << 16;
    return __builtin_bit_cast(float, u);
}
__device__ __forceinline__ float fast_tanh(float x){
    float e = __expf(2.f * x);
    return 1.f - 2.f * __builtin_amdgcn_rcpf(e + 1.f);
}
__device__ __forceinline__ float fast_sig(float x){
    return __builtin_amdgcn_rcpf(1.f + __expf(-x));
}

// ---- prep: X -> bf16 hi/lo split ----
__global__ void prep_x(const float* __restrict__ X, u16* __restrict__ Xhi, u16* __restrict__ Xlo){
    size_t g = (size_t)blockIdx.x * blockDim.x + threadIdx.x;   // one float4 per thread
    float4 v = ((const float4*)X)[g];
    u16 h0 = f2bf(v.x), h1 = f2bf(v.y), h2 = f2bf(v.z), h3 = f2bf(v.w);
    ushort4 hh; hh.x = h0; hh.y = h1; hh.z = h2; hh.w = h3;
    ushort4 ll;
    ll.x = f2bf(v.x - bf2f(h0)); ll.y = f2bf(v.y - bf2f(h1));
    ll.z = f2bf(v.z - bf2f(h2)); ll.w = f2bf(v.w - bf2f(h3));
    ((ushort4*)Xhi)[g] = hh;
    ((ushort4*)Xlo)[g] = ll;
}

// ---- prep: transpose+split weights into WT[c][k], k = [Wh rows | Wx rows] ----
__global__ void prep_w(const float* __restrict__ Wx, const float* __restrict__ Wh,
                       u16* __restrict__ WThi, u16* __restrict__ WTlo){
    int c = blockIdx.x;  // 0..2047
    for (int kk = threadIdx.x; kk < KTOT; kk += blockDim.x){
        float w = (kk < 512) ? Wh[(size_t)kk * K4H + c] : Wx[(size_t)(kk - 512) * K4H + c];
        u16 hi = f2bf(w);
        u16 lo = f2bf(w - bf2f(hi));
        WThi[(size_t)c * KTOT + kk] = hi;
        WTlo[(size_t)c * KTOT + kk] = lo;
    }
}

// ---- prep: zero h buf0, barrier counters, and out row t=0 ----
__global__ void prep_misc(u16* __restrict__ hH, u16* __restrict__ hL,
                          u32* __restrict__ cbar, float* __restrict__ out){
    int i = blockIdx.x * blockDim.x + threadIdx.x;   // 65536 threads
    hH[i] = 0; hL[i] = 0;
    if (i < 256) cbar[i] = 0;
    int b = i >> 9, j = i & 511;
    out[(size_t)b * (TT * HH) + j] = 0.f;            // out[b][0][j]
}

// 3-product split-bf16 MFMA (hi*hi + hi*lo + lo*hi)
#define MF3(ACC, AH, AL, BH, BL) \
    ACC = __builtin_amdgcn_mfma_f32_32x32x16_bf16(AH, BH, ACC, 0, 0, 0); \
    ACC = __builtin_amdgcn_mfma_f32_32x32x16_bf16(AH, BL, ACC, 0, 0, 0); \
    ACC = __builtin_amdgcn_mfma_f32_32x32x16_bf16(AL, BH, ACC, 0, 0, 0);

// ---- main cooperative kernel: 256 WGs (1/CU), 256 thr, 511 steps ----
// WG = (bt = batch tile of 32, js = 8 h-indices). C-tile 32x32: row m = batch, col n = g*8+jl.
// Split-K over 4 waves. B-frags in NAMED registers (no arrays -> no scratch).
// Custom grid barrier: 16 distributed agent-scope counters; h via sc1 atomic ld/st.
__global__ void __launch_bounds__(256, 1) lstm_main(
    const u16* __restrict__ Xhi, const u16* __restrict__ Xlo,
    const u16* __restrict__ WThi, const u16* __restrict__ WTlo,
    const float* __restrict__ bias,
    u16* __restrict__ hH, u16* __restrict__ hL,
    u32* __restrict__ cbar,
    float* __restrict__ out)
{
    __shared__ float red[4][32][36];   // pitch 36: <=2-way bank aliasing

    const int tid  = threadIdx.x;
    const int lane = tid & 63;
    const int kh   = tid >> 6;         // wave id = K-split index
    const int wid  = blockIdx.x;
    const int bt   = wid & 3;          // batch tile (32 batches)
    const int js   = wid >> 2;         // j-set (8 h-indices)

    const int n  = lane & 31;          // MFMA row/col within tile
    const int kg = (lane >> 5) * 8;    // k sub-group

    // B fragments: named scalars -> guaranteed register-resident for all 511 steps
    const int c_n = (n >> 3) * 512 + js * 8 + (n & 7);   // global column for frag col n
    const size_t wrow = (size_t)c_n * KTOT;

#define LDB(NH, NL, KK) \
    bfrag NH = __builtin_bit_cast(bfrag, *(const ushortx8*)(WThi + wrow + (KK))); \
    bfrag NL = __builtin_bit_cast(bfrag, *(const ushortx8*)(WTlo + wrow + (KK)));

    LDB(bh0, bl0, kh*128 + 0*16 + kg)      // h-part weights
    LDB(bh1, bl1, kh*128 + 1*16 + kg)
    LDB(bh2, bl2, kh*128 + 2*16 + kg)
    LDB(bh3, bl3, kh*128 + 3*16 + kg)
    LDB(bh4, bl4, kh*128 + 4*16 + kg)
    LDB(bh5, bl5, kh*128 + 5*16 + kg)
    LDB(bh6, bl6, kh*128 + 6*16 + kg)
    LDB(bh7, bl7, kh*128 + 7*16 + kg)
    LDB(cx0, dx0, 512 + kh*128 + 0*16 + kg)  // x-part weights
    LDB(cx1, dx1, 512 + kh*128 + 1*16 + kg)
    LDB(cx2, dx2, 512 + kh*128 + 2*16 + kg)
    LDB(cx3, dx3, 512 + kh*128 + 3*16 + kg)
    LDB(cx4, dx4, 512 + kh*128 + 4*16 + kg)
    LDB(cx5, dx5, 512 + kh*128 + 5*16 + kg)
    LDB(cx6, dx6, 512 + kh*128 + 6*16 + kg)
    LDB(cx7, dx7, 512 + kh*128 + 7*16 + kg)

    // A-fragment addressing (row m = n lane field)
    const int bgm = bt * 32 + n;                        // global batch row for A
    const size_t xrow = (size_t)bgm * (TT * 512);       // + t*512 + k
    const int xk    = kh * 128 + kg;
    const int hbase = bgm * 512 + kh * 128 + kg;

    // gate threads: tid<128, each owns (batch, 2 adjacent j) so h stores are u32 atomics
    const int blt = tid >> 2;            // 0..31 batch local (tid<128)
    const int jp  = (tid & 3) * 2;       // 0,2,4,6
    const int bg  = bt * 32 + blt;
    const int jg0 = js * 8 + jp;
    float biasr[8];
    if (tid < 128){
#pragma unroll
        for (int g = 0; g < 4; g++){
            biasr[2*g]   = bias[g * 512 + jg0];
            biasr[2*g+1] = bias[g * 512 + jg0 + 1];
        }
    }

    float cs0 = 0.f, cs1 = 0.f;
    facc acc0 = {0.f,0.f,0.f,0.f,0.f,0.f,0.f,0.f,0.f,0.f,0.f,0.f,0.f,0.f,0.f,0.f};
    facc acc1 = {0.f,0.f,0.f,0.f,0.f,0.f,0.f,0.f,0.f,0.f,0.f,0.f,0.f,0.f,0.f,0.f};

#define XSTEP(I, ACC, BH, BL) do{ \
    bfrag ah = __builtin_bit_cast(bfrag, *(const ushortx8*)(xh + I*16)); \
    bfrag al = __builtin_bit_cast(bfrag, *(const ushortx8*)(xl + I*16)); \
    MF3(ACC, ah, al, BH, BL) }while(0)

#define HSTEP(I, ACC, BH, BL) do{ \
    u64* p = (u64*)(hhp + I*16); \
    u64* q = (u64*)(hlp + I*16); \
    u64x2 va, vb; \
    va.x = __hip_atomic_load(p,   __ATOMIC_RELAXED, __HIP_MEMORY_SCOPE_AGENT); \
    va.y = __hip_atomic_load(p+1, __ATOMIC_RELAXED, __HIP_MEMORY_SCOPE_AGENT); \
    vb.x = __hip_atomic_load(q,   __ATOMIC_RELAXED, __HIP_MEMORY_SCOPE_AGENT); \
    vb.y = __hip_atomic_load(q+1, __ATOMIC_RELAXED, __HIP_MEMORY_SCOPE_AGENT); \
    bfrag ah = __builtin_bit_cast(bfrag, va); \
    bfrag al = __builtin_bit_cast(bfrag, vb); \
    MF3(ACC, ah, al, BH, BL) }while(0)

    for (int t = 0; t < 511; t++){
        // ---- x-part GEMM (independent of h): issue BEFORE barrier spin ----
        const u16* xh = Xhi + xrow + (size_t)t * 512 + xk;
        const u16* xl = Xlo + xrow + (size_t)t * 512 + xk;
        XSTEP(0, acc0, cx0, dx0);
        XSTEP(1, acc1, cx1, dx1);
        XSTEP(2, acc0, cx2, dx2);
        XSTEP(3, acc1, cx3, dx3);
        XSTEP(4, acc0, cx4, dx4);
        XSTEP(5, acc1, cx5, dx5);
        XSTEP(6, acc0, cx6, dx6);
        XSTEP(7, acc1, cx7, dx7);

        // ---- grid barrier: wait until all WGs published h_t ----
        if (t){
            if (tid < 64){
                const u32 tgt = 16u * (u32)t;
                bool ok;
                do {
                    u32 c = tgt;
                    if (lane < 16)
                        c = __hip_atomic_load(&cbar[lane * 16], __ATOMIC_RELAXED,
                                              __HIP_MEMORY_SCOPE_AGENT);
                    ok = (bool)__all((int)(c >= tgt));
                } while (!ok);
            }
            __syncthreads();
        }

        // ---- h-part GEMM (sc1 loads bypass stale caches) ----
        u16* hhp = hH + (size_t)(t & 1) * (BB * 512) + hbase;
        u16* hlp = hL + (size_t)(t & 1) * (BB * 512) + hbase;
        HSTEP(0, acc0, bh0, bl0);
        HSTEP(1, acc1, bh1, bl1);
        HSTEP(2, acc0, bh2, bl2);
        HSTEP(3, acc1, bh3, bl3);
        HSTEP(4, acc0, bh4, bl4);
        HSTEP(5, acc1, bh5, bl5);
        HSTEP(6, acc0, bh6, bl6);
        HSTEP(7, acc1, bh7, bl7);

        // ---- split-K reduction via LDS ----
#pragma unroll
        for (int r = 0; r < 16; r++){
            int mrow = (r & 3) + 8 * (r >> 2) + 4 * (lane >> 5);  // verified C layout
            red[kh][mrow][n] = acc0[r] + acc1[r];
        }
#pragma unroll
        for (int r = 0; r < 16; r++){ acc0[r] = 0.f; acc1[r] = 0.f; }
        __syncthreads();   // (C) red visible to gate threads

        // ---- gates + state update: 2 adjacent j per thread, tid<128 ----
        if (tid < 128){
            float v0[4], v1[4];
#pragma unroll
            for (int g = 0; g < 4; g++){
                int nn = g * 8 + jp;
                v0[g] = red[0][blt][nn]   + red[1][blt][nn]   + red[2][blt][nn]   + red[3][blt][nn]   + biasr[2*g];
                v1[g] = red[0][blt][nn+1] + red[1][blt][nn+1] + red[2][blt][nn+1] + red[3][blt][nn+1] + biasr[2*g+1];
            }
            float f0 = fast_sig(fast_tanh(v0[0])), f1 = fast_sig(fast_tanh(v1[0]));
            float g0 = fast_tanh(fast_tanh(v0[1])), g1 = fast_tanh(fast_tanh(v1[1]));
            float i0 = fast_sig(fast_tanh(v0[2])), i1 = fast_sig(fast_tanh(v1[2]));
            float o0 = fast_sig(fast_tanh(v0[3])), o1 = fast_sig(fast_tanh(v1[3]));
            float hn0 = o0 * fast_tanh(cs0);
            float hn1 = o1 * fast_tanh(cs1);
            cs0 = f0 * cs0 + g0 * i0;
            cs1 = f1 * cs1 + g1 * i1;

            // out: plain store (visible at kernel end)
            float2 ov; ov.x = hn0; ov.y = hn1;
            *(float2*)(out + (size_t)bg * (TT * HH) + (size_t)(t + 1) * HH + jg0) = ov;

            // h hi/lo: packed u32 agent-scope stores (write-through to IC)
            u16 h0i = f2bf(hn0), h1i = f2bf(hn1);
            u32 hpack = (u32)h0i | ((u32)h1i << 16);
            u16 l0i = f2bf(hn0 - bf2f(h0i)), l1i = f2bf(hn1 - bf2f(h1i));
            u32 lpack = (u32)l0i | ((u32)l1i << 16);
            size_t hidx = (size_t)((t + 1) & 1) * (BB * 512) + (size_t)bg * 512 + jg0;
            __hip_atomic_store((u32*)(hH + hidx), hpack, __ATOMIC_RELAXED, __HIP_MEMORY_SCOPE_AGENT);
            __hip_atomic_store((u32*)(hL + hidx), lpack, __ATOMIC_RELAXED, __HIP_MEMORY_SCOPE_AGENT);
        }

        __syncthreads();   // (A) all h stores issued + vmcnt-drained before arrival
        if (tid == 0)
            __hip_atomic_fetch_add(&cbar[(wid & 15) * 16], 1u, __ATOMIC_RELEASE,
                                   __HIP_MEMORY_SCOPE_AGENT);
    }
}

extern "C" void kernel_launch(void* const* d_in, const int* in_sizes, int n_in,
                              void* d_out, int out_size, void* d_ws, size_t ws_size,
                              hipStream_t stream)
{
    const float* X    = (const float*)d_in[0];
    const float* Wx   = (const float*)d_in[1];
    const float* Wh   = (const float*)d_in[2];
    const float* bias = (const float*)d_in[3];
    float* out = (float*)d_out;

    char* ws = (char*)d_ws;
    u16* Xhi  = (u16*)(ws);                      // 64 MiB
    u16* Xlo  = (u16*)(ws + 67108864ull);        // 64 MiB
    u16* WThi = (u16*)(ws + 134217728ull);       // 4 MiB
    u16* WTlo = (u16*)(ws + 138412032ull);       // 4 MiB
    u16* hHp  = (u16*)(ws + 142606336ull);       // 256 KiB (double buffered)
    u16* hLp  = (u16*)(ws + 142868480ull);       // 256 KiB
    u32* cbar = (u32*)(ws + 143130624ull);       // 1 KiB barrier counters

    hipLaunchKernelGGL(prep_x,    dim3(32768), dim3(256), 0, stream, X, Xhi, Xlo);
    hipLaunchKernelGGL(prep_w,    dim3(2048),  dim3(256), 0, stream, Wx, Wh, WThi, WTlo);
    hipLaunchKernelGGL(prep_misc, dim3(256),   dim3(256), 0, stream, hHp, hLp, cbar, out);

    void* args[] = { (void*)&Xhi, (void*)&Xlo, (void*)&WThi, (void*)&WTlo,
                     (void*)&bias, (void*)&hHp, (void*)&hLp, (void*)&cbar, (void*)&out };
    hipLaunchCooperativeKernel(lstm_main, dim3(256), dim3(256), args, 0, stream);
}